// Round 3
// baseline (234.121 us; speedup 1.0000x reference)
//
#include <hip/hip_runtime.h>

typedef __bf16 bf16x8 __attribute__((ext_vector_type(8)));
typedef float f32x4 __attribute__((ext_vector_type(4)));

#define BN_EPS 1e-5f

__device__ __forceinline__ unsigned short f2bf(float f) {
    union { float f; unsigned u; } x; x.f = f;
    unsigned r = x.u + 0x7fffu + ((x.u >> 16) & 1u);
    return (unsigned short)(r >> 16);
}

__device__ __forceinline__ unsigned pk_bf16(float lo, float hi) {
    unsigned r;
    asm("v_cvt_pk_bf16_f32 %0, %1, %2" : "=v"(r) : "v"(lo), "v"(hi));
    return r;
}

// ---------------- prepass: fold BN scale into pointwise weights (bf16), compute beta ----
__global__ void prep_kernel(const float* __restrict__ pw0, const float* __restrict__ pw1,
                            const float* __restrict__ w2,
                            const float* __restrict__ s0, const float* __restrict__ b0,
                            const float* __restrict__ m0, const float* __restrict__ v0,
                            const float* __restrict__ s1, const float* __restrict__ b1,
                            const float* __restrict__ m1, const float* __restrict__ v1,
                            const float* __restrict__ s2, const float* __restrict__ b2,
                            const float* __restrict__ m2, const float* __restrict__ v2,
                            unsigned short* __restrict__ wf0, unsigned short* __restrict__ wf1,
                            unsigned short* __restrict__ wf2, float* __restrict__ beta) {
    int o = blockIdx.x;     // 0..255
    int t = threadIdx.x;    // 0..255
    float inv0 = s0[o] * rsqrtf(v0[o] + BN_EPS);
    float inv1 = s1[o] * rsqrtf(v1[o] + BN_EPS);
    float inv2 = s2[o] * rsqrtf(v2[o] + BN_EPS);
    if (t == 0) {
        beta[0 * 256 + o] = b0[o] - m0[o] * inv0;
        beta[1 * 256 + o] = b1[o] - m1[o] * inv1;
        beta[2 * 256 + o] = b2[o] - m2[o] * inv2;
    }
    if (t < 128) {
        wf0[o * 128 + t] = f2bf(pw0[o * 128 + t] * inv0);
        wf1[o * 128 + t] = f2bf(pw1[o * 128 + t] * inv1);
    }
    wf2[o * 256 + t] = f2bf(w2[o * 256 + t] * inv2);
}

// ---------------- staging helpers ----------------
// LDS B-tile: [64 px][512 K] bf16, px-major (1024 B/px row), 16-B cols swizzled byte ^= (px&7)<<4.
// K layout: [0,128)=dw(rgb), [128,256)=dw(ir), [256,512)=raw x.

__device__ __forceinline__ void stage_loads(const float* xb, int c, bool hm, bool hp,
                                            float4 rm[2], float4 rc[2], float4 rp[2]) {
#pragma unroll
    for (int k2 = 0; k2 < 2; ++k2) {
        const float* xc = xb + (long)(c + k2) * 4096;
        rm[k2] = hm ? *(const float4*)(xc - 64) : make_float4(0.f, 0.f, 0.f, 0.f);
        rc[k2] = *(const float4*)(xc);
        rp[k2] = hp ? *(const float4*)(xc + 64) : make_float4(0.f, 0.f, 0.f, 0.f);
    }
}

__device__ __forceinline__ void stage_cw(char* lds, const float* __restrict__ dw0,
                                         const float* __restrict__ dw1,
                                         int c, int g, int px0,
                                         const float4 rm[2], const float4 rc[2], const float4 rp[2]) {
    float y[2][4];
#pragma unroll
    for (int k2 = 0; k2 < 2; ++k2) {
        const int cg = c + k2;
        const float* dwp = (cg < 128) ? (dw0 + cg * 9) : (dw1 + (cg - 128) * 9);
        float4 m = rm[k2], cr = rc[k2], p = rp[k2];
        float lm = __shfl_up(m.w, 4), lc = __shfl_up(cr.w, 4), lp = __shfl_up(p.w, 4);
        float Rm = __shfl_down(m.x, 4), Rc = __shfl_down(cr.x, 4), Rp = __shfl_down(p.x, 4);
        if (g == 0)  { lm = 0.f; lc = 0.f; lp = 0.f; }
        if (g == 15) { Rm = 0.f; Rc = 0.f; Rp = 0.f; }
        const float w0 = dwp[0], w1 = dwp[1], w2 = dwp[2];
        const float w3 = dwp[3], w4 = dwp[4], w5 = dwp[5];
        const float w6 = dwp[6], w7 = dwp[7], w8 = dwp[8];
        y[k2][0] = w0*lm   + w1*m.x + w2*m.y + w3*lc   + w4*cr.x + w5*cr.y + w6*lp   + w7*p.x + w8*p.y;
        y[k2][1] = w0*m.x  + w1*m.y + w2*m.z + w3*cr.x + w4*cr.y + w5*cr.z + w6*p.x  + w7*p.y + w8*p.z;
        y[k2][2] = w0*m.y  + w1*m.z + w2*m.w + w3*cr.y + w4*cr.z + w5*cr.w + w6*p.y  + w7*p.z + w8*p.w;
        y[k2][3] = w0*m.z  + w1*m.w + w2*Rm  + w3*cr.z + w4*cr.w + w5*Rc   + w6*p.z  + w7*p.w + w8*Rp;
    }
    const int colb = (c >> 3) * 16;       // K index == channel for dw region
    const int sub  = (c & 7) * 2;         // 4-B aligned (c even)
#pragma unroll
    for (int j = 0; j < 4; ++j) {
        const int px = px0 + j;
        *(unsigned*)(lds + px * 1024 + ((colb ^ ((px & 7) << 4))) + sub) = pk_bf16(y[0][j], y[1][j]);
    }
}

// ---------------- GEMM phase: bulk-A + LDS-B + MFMA ----------------
template<int NK>
__device__ __forceinline__ void gemm_phase(const char* lds, const unsigned short* __restrict__ W,
                                           int Ke, int qb, int wot, int ph, int l15, int l4,
                                           f32x4 acc[2][2]) {
    bf16x8 af[NK][2];
    const unsigned short* wb = W + (wot * 32 + l15) * Ke + l4 * 8;
#pragma unroll
    for (int kk = 0; kk < NK; ++kk)
#pragma unroll
        for (int ot = 0; ot < 2; ++ot)
            af[kk][ot] = *(const bf16x8*)(wb + ot * 16 * Ke + kk * 32);
#pragma unroll
    for (int kk = 0; kk < NK; ++kk) {
        bf16x8 bb[2];
#pragma unroll
        for (int tp = 0; tp < 2; ++tp) {
            const int px = ph * 32 + tp * 16 + l15;
            bb[tp] = *(const bf16x8*)(lds + px * 1024 + ((qb + kk * 64 + l4 * 16) ^ ((px & 7) << 4)));
        }
#pragma unroll
        for (int ot = 0; ot < 2; ++ot)
#pragma unroll
            for (int tp = 0; tp < 2; ++tp)
                acc[ot][tp] = __builtin_amdgcn_mfma_f32_16x16x32_bf16(af[kk][ot], bb[tp], acc[ot][tp], 0, 0, 0);
    }
}

__device__ __forceinline__ void epilogue(const f32x4 acc[2][2], float ce, const float* __restrict__ bp,
                                         int wot, int l4, f32x4 res[2][2]) {
#pragma unroll
    for (int ot = 0; ot < 2; ++ot)
#pragma unroll
        for (int j = 0; j < 4; ++j) {
            const int o = wot * 32 + ot * 16 + l4 * 4 + j;
            const float bet = bp[o];
#pragma unroll
            for (int tp = 0; tp < 2; ++tp) {
                float v = acc[ot][tp][j] + bet;
                float sig = __builtin_amdgcn_rcpf(1.f + __expf(-v));
                res[ot][tp][j] += ce * (v * sig);
            }
        }
}

// ---------------- main fused kernel: 1 WG per (b,h) row, 16 waves ----------------------
__global__ __launch_bounds__(1024, 4)
void fused_kernel(const float* __restrict__ x,
                  const float* __restrict__ wts, const int* __restrict__ idx,
                  const float* __restrict__ dw0, const float* __restrict__ dw1,
                  const unsigned short* __restrict__ wf0,
                  const unsigned short* __restrict__ wf1,
                  const unsigned short* __restrict__ wf2,
                  const float* __restrict__ beta,
                  float* __restrict__ out) {
    __shared__ __align__(16) char lds[64 * 1024];

    const int tid  = threadIdx.x;
    const int wave = tid >> 6;
    const int lane = tid & 63;

    // XCD-aware swizzle: consecutive h (same b) stay on one XCD for L2 reuse.
    const int bid = blockIdx.x;
    const int nb  = ((bid & 7) << 8) | (bid >> 3);   // 2048 = 8 * 256, bijective
    const int b   = nb >> 6;
    const int h   = nb & 63;

    // per-batch expert coefficients (uniform per block)
    float c0 = 0.f, c1 = 0.f, c2 = 0.f;
#pragma unroll
    for (int t = 0; t < 2; ++t) {
        int e = idx[b * 2 + t];
        float w = wts[b * 2 + t];
        if (e == 0) c0 += w;
        else if (e == 1) c1 += w;
        else if (e == 2) c2 += w;
    }

    const long rowBase = (long)b * 1048576L;         // batch stride 256*4096 floats

    const int g   = lane >> 2;                       // px-group 0..15
    const int kq  = lane & 3;
    const int px0 = g * 4;
    const int l15 = lane & 15;
    const int l4  = lane >> 4;
    const int wot = wave & 7;                        // outch tile 0..7
    const int ph  = wave >> 3;                       // px half 0..1

    const float* xb = x + rowBase + h * 64 + px0;
    const bool hm = (h > 0), hp = (h < 63);

    // ---------- s0: stage channels [0,128) -> dw K[0,128) (exposed once) ----------
    {
        float4 m0[2], c0r[2], p0[2];
        const int c = wave * 8 + kq * 2;
        stage_loads(xb, c, hm, hp, m0, c0r, p0);
        stage_cw(lds, dw0, dw1, c, g, px0, m0, c0r, p0);
    }
    __syncthreads();

    f32x4 res[2][2];
#pragma unroll
    for (int ot = 0; ot < 2; ++ot)
#pragma unroll
        for (int tp = 0; tp < 2; ++tp)
            res[ot][tp] = (f32x4){0.f, 0.f, 0.f, 0.f};

    // issue s1 x-loads early (complete during e0)
    float4 m1[2], c1r[2], p1[2];
    stage_loads(xb, 128 + wave * 8 + kq * 2, hm, hp, m1, c1r, p1);

    // ---------- e0 ----------
    {
        f32x4 acc[2][2];
#pragma unroll
        for (int ot = 0; ot < 2; ++ot)
#pragma unroll
            for (int tp = 0; tp < 2; ++tp)
                acc[ot][tp] = (f32x4){0.f, 0.f, 0.f, 0.f};
        gemm_phase<4>(lds, wf0, 128, 0, wot, ph, l15, l4, acc);
        epilogue(acc, c0, beta, wot, l4, res);
    }

    // s1 compute + write dw K[128,256)  (disjoint from e0's read region)
    stage_cw(lds, dw0, dw1, 128 + wave * 8 + kq * 2, g, px0, m1, c1r, p1);
    __syncthreads();

    // issue s2 raw loads early (center rows, L2-hot; complete during e1)
    float4 r0, r1, r2, r3;
    {
        const int k0 = wave * 16 + kq * 4;
        r0 = *(const float4*)(xb + (long)(k0 + 0) * 4096);
        r1 = *(const float4*)(xb + (long)(k0 + 1) * 4096);
        r2 = *(const float4*)(xb + (long)(k0 + 2) * 4096);
        r3 = *(const float4*)(xb + (long)(k0 + 3) * 4096);
    }

    // ---------- e1 ----------
    {
        f32x4 acc[2][2];
#pragma unroll
        for (int ot = 0; ot < 2; ++ot)
#pragma unroll
            for (int tp = 0; tp < 2; ++tp)
                acc[ot][tp] = (f32x4){0.f, 0.f, 0.f, 0.f};
        gemm_phase<4>(lds, wf1, 128, 256, wot, ph, l15, l4, acc);
        epilogue(acc, c1, beta + 256, wot, l4, res);
    }

    // s2 write: raw K[256,512)  (disjoint from e1's read region)
    {
        const int k0 = wave * 16 + kq * 4;
        const int Kg = 256 + k0;
        const int colb = (Kg >> 3) * 16;
        const int sub  = (Kg & 7) * 2;               // 8-B aligned (k0 % 4 == 0)
        // px j: pack channels k0..k0+3
        {
            const int px = px0 + 0;
            *(uint2*)(lds + px * 1024 + ((colb ^ ((px & 7) << 4))) + sub) =
                make_uint2(pk_bf16(r0.x, r1.x), pk_bf16(r2.x, r3.x));
        }
        {
            const int px = px0 + 1;
            *(uint2*)(lds + px * 1024 + ((colb ^ ((px & 7) << 4))) + sub) =
                make_uint2(pk_bf16(r0.y, r1.y), pk_bf16(r2.y, r3.y));
        }
        {
            const int px = px0 + 2;
            *(uint2*)(lds + px * 1024 + ((colb ^ ((px & 7) << 4))) + sub) =
                make_uint2(pk_bf16(r0.z, r1.z), pk_bf16(r2.z, r3.z));
        }
        {
            const int px = px0 + 3;
            *(uint2*)(lds + px * 1024 + ((colb ^ ((px & 7) << 4))) + sub) =
                make_uint2(pk_bf16(r0.w, r1.w), pk_bf16(r2.w, r3.w));
        }
    }
    __syncthreads();

    // ---------- e2 ----------
    {
        f32x4 acc[2][2];
#pragma unroll
        for (int ot = 0; ot < 2; ++ot)
#pragma unroll
            for (int tp = 0; tp < 2; ++tp)
                acc[ot][tp] = (f32x4){0.f, 0.f, 0.f, 0.f};
        gemm_phase<8>(lds, wf2, 256, 512, wot, ph, l15, l4, acc);
        epilogue(acc, c2, beta + 512, wot, l4, res);
    }

    // ---------- store: transpose through LDS, 256-B coalesced lines ----------
    float* lf = (float*)lds;
    const long outB = rowBase + h * 64;
    __syncthreads();                                  // all waves done reading B-tile
#pragma unroll
    for (int r = 0; r < 2; ++r) {
        if ((wot >> 2) == r) {
#pragma unroll
            for (int ot = 0; ot < 2; ++ot)
#pragma unroll
                for (int j = 0; j < 4; ++j) {
                    const int row = (wot & 3) * 32 + ot * 16 + l4 * 4 + j;   // 0..127
#pragma unroll
                    for (int tp = 0; tp < 2; ++tp)
                        lf[row * 68 + ph * 32 + tp * 16 + l15] = res[ot][tp][j];
                }
        }
        __syncthreads();
        {
            const int row = tid >> 3;                 // 0..127
            const int col = (tid & 7) * 8;            // float index
            float4 v0 = *(float4*)&lf[row * 68 + col];
            float4 v1 = *(float4*)&lf[row * 68 + col + 4];
            float* op = out + outB + (long)(r * 128 + row) * 4096 + col;
            *(float4*)op = v0;
            *(float4*)(op + 4) = v1;
        }
        __syncthreads();
    }
}

extern "C" void kernel_launch(void* const* d_in, const int* in_sizes, int n_in,
                              void* d_out, int out_size, void* d_ws, size_t ws_size,
                              hipStream_t stream) {
    const float* x    = (const float*)d_in[0];
    const float* wts  = (const float*)d_in[1];
    const int*   idx  = (const int*)d_in[2];
    const float* dw0  = (const float*)d_in[3];
    const float* pw0  = (const float*)d_in[4];
    const float* s0   = (const float*)d_in[5];
    const float* b0   = (const float*)d_in[6];
    const float* m0   = (const float*)d_in[7];
    const float* v0   = (const float*)d_in[8];
    const float* dw1  = (const float*)d_in[9];
    const float* pw1  = (const float*)d_in[10];
    const float* s1   = (const float*)d_in[11];
    const float* b1   = (const float*)d_in[12];
    const float* m1   = (const float*)d_in[13];
    const float* v1   = (const float*)d_in[14];
    const float* w2   = (const float*)d_in[15];
    const float* s2   = (const float*)d_in[16];
    const float* b2   = (const float*)d_in[17];
    const float* m2   = (const float*)d_in[18];
    const float* v2   = (const float*)d_in[19];

    unsigned short* wf0  = (unsigned short*)d_ws;
    unsigned short* wf1  = wf0 + 256 * 128;
    unsigned short* wf2  = wf1 + 256 * 128;
    float*          beta = (float*)(wf2 + 256 * 256);

    prep_kernel<<<256, 256, 0, stream>>>(pw0, pw1, w2,
                                         s0, b0, m0, v0,
                                         s1, b1, m1, v1,
                                         s2, b2, m2, v2,
                                         wf0, wf1, wf2, beta);

    fused_kernel<<<2048, 1024, 0, stream>>>(x, wts, idx, dw0, dw1,
                                            wf0, wf1, wf2, beta, (float*)d_out);
}

// Round 4
// 221.741 us; speedup vs baseline: 1.0558x; 1.0558x over previous
//
#include <hip/hip_runtime.h>

typedef __bf16 bf16x8 __attribute__((ext_vector_type(8)));
typedef float f32x4 __attribute__((ext_vector_type(4)));

#define BN_EPS 1e-5f

__device__ __forceinline__ unsigned short f2bf(float f) {
    union { float f; unsigned u; } x; x.f = f;
    unsigned r = x.u + 0x7fffu + ((x.u >> 16) & 1u);
    return (unsigned short)(r >> 16);
}

__device__ __forceinline__ unsigned pk_bf16(float lo, float hi) {
    unsigned r;
    asm("v_cvt_pk_bf16_f32 %0, %1, %2" : "=v"(r) : "v"(lo), "v"(hi));
    return r;
}

__device__ __forceinline__ void gld_lds16(const void* g, void* l) {
    __builtin_amdgcn_global_load_lds((const __attribute__((address_space(1))) unsigned int*)g,
                                     (__attribute__((address_space(3))) unsigned int*)l,
                                     16, 0, 0);
}

// ---------------- prepass: fold BN scale into pointwise weights (bf16), compute beta ----
__global__ void prep_kernel(const float* __restrict__ pw0, const float* __restrict__ pw1,
                            const float* __restrict__ w2,
                            const float* __restrict__ s0, const float* __restrict__ b0,
                            const float* __restrict__ m0, const float* __restrict__ v0,
                            const float* __restrict__ s1, const float* __restrict__ b1,
                            const float* __restrict__ m1, const float* __restrict__ v1,
                            const float* __restrict__ s2, const float* __restrict__ b2,
                            const float* __restrict__ m2, const float* __restrict__ v2,
                            unsigned short* __restrict__ wf0, unsigned short* __restrict__ wf1,
                            unsigned short* __restrict__ wf2, float* __restrict__ beta) {
    int o = blockIdx.x;     // 0..255
    int t = threadIdx.x;    // 0..255
    float inv0 = s0[o] * rsqrtf(v0[o] + BN_EPS);
    float inv1 = s1[o] * rsqrtf(v1[o] + BN_EPS);
    float inv2 = s2[o] * rsqrtf(v2[o] + BN_EPS);
    if (t == 0) {
        beta[0 * 256 + o] = b0[o] - m0[o] * inv0;
        beta[1 * 256 + o] = b1[o] - m1[o] * inv1;
        beta[2 * 256 + o] = b2[o] - m2[o] * inv2;
    }
    if (t < 128) {
        wf0[o * 128 + t] = f2bf(pw0[o * 128 + t] * inv0);
        wf1[o * 128 + t] = f2bf(pw1[o * 128 + t] * inv1);
    }
    wf2[o * 256 + t] = f2bf(w2[o * 256 + t] * inv2);
}

// ---------------- K1: depthwise -> swizzled bf16 feat tiles ----------------
// feat tile (per (b,h)): 32 KB = [64 px][512 B], dw K in [0,256), 16-B cols XOR-swizzled
// byte ^= (px&7)<<4. Dumped linearly so K2 can DMA it back with linear LDS dest.
__global__ __launch_bounds__(512, 4)
void dw_stage_kernel(const float* __restrict__ x,
                     const float* __restrict__ dw0, const float* __restrict__ dw1,
                     char* __restrict__ feat) {
    __shared__ __align__(16) char lds[64 * 512];

    const int tid  = threadIdx.x;
    const int wave = tid >> 6;
    const int lane = tid & 63;

    const int bid = blockIdx.x;
    const int nb  = ((bid & 7) << 8) | (bid >> 3);   // XCD swizzle, bijective on 2048
    const int b   = nb >> 6;
    const int h   = nb & 63;

    const long rowBase = (long)b * 1048576L;
    const int g   = lane >> 2;                       // px-group 0..15 (4 px)
    const int kq  = lane & 3;
    const int px0 = g * 4;
    const float* xb = x + rowBase + h * 64 + px0;
    const bool hm = (h > 0), hp = (h < 63);

#pragma unroll
    for (int i = 0; i < 2; ++i) {
        const int k0 = wave * 32 + i * 16 + kq * 4;  // 4 ch: k0..k0+3
        unsigned dw_p[2][4];
#pragma unroll
        for (int pr = 0; pr < 2; ++pr) {
            float y[2][4];
#pragma unroll
            for (int k2 = 0; k2 < 2; ++k2) {
                const int k = k0 + pr * 2 + k2;
                const float* dwp = (k < 128) ? (dw0 + k * 9) : (dw1 + (k - 128) * 9);
                const float* xc = xb + (long)k * 4096;
                float4 rm = hm ? *(const float4*)(xc - 64) : make_float4(0.f, 0.f, 0.f, 0.f);
                float4 rc = *(const float4*)(xc);
                float4 rp = hp ? *(const float4*)(xc + 64) : make_float4(0.f, 0.f, 0.f, 0.f);
                float lm = __shfl_up(rm.w, 4), lc = __shfl_up(rc.w, 4), lp = __shfl_up(rp.w, 4);
                float Rm = __shfl_down(rm.x, 4), Rc = __shfl_down(rc.x, 4), Rp = __shfl_down(rp.x, 4);
                if (g == 0)  { lm = 0.f; lc = 0.f; lp = 0.f; }
                if (g == 15) { Rm = 0.f; Rc = 0.f; Rp = 0.f; }
                const float w0 = dwp[0], w1 = dwp[1], w2 = dwp[2];
                const float w3 = dwp[3], w4 = dwp[4], w5 = dwp[5];
                const float w6 = dwp[6], w7 = dwp[7], w8 = dwp[8];
                y[k2][0] = w0*lm   + w1*rm.x + w2*rm.y + w3*lc   + w4*rc.x + w5*rc.y + w6*lp   + w7*rp.x + w8*rp.y;
                y[k2][1] = w0*rm.x + w1*rm.y + w2*rm.z + w3*rc.x + w4*rc.y + w5*rc.z + w6*rp.x + w7*rp.y + w8*rp.z;
                y[k2][2] = w0*rm.y + w1*rm.z + w2*rm.w + w3*rc.y + w4*rc.z + w5*rc.w + w6*rp.y + w7*rp.z + w8*rp.w;
                y[k2][3] = w0*rm.z + w1*rm.w + w2*Rm   + w3*rc.z + w4*rc.w + w5*Rc   + w6*rp.z + w7*rp.w + w8*Rp;
            }
#pragma unroll
            for (int j = 0; j < 4; ++j)
                dw_p[pr][j] = pk_bf16(y[0][j], y[1][j]);
        }
        const int colb = (k0 >> 3) * 16;
        const int sub  = (k0 & 4) * 2;               // 0 or 8
#pragma unroll
        for (int j = 0; j < 4; ++j) {
            const int px = px0 + j;
            *(uint2*)(lds + px * 512 + ((colb ^ ((px & 7) << 4))) + sub) =
                make_uint2(dw_p[0][j], dw_p[1][j]);
        }
    }
    __syncthreads();

    // linear dump: 32 KB, 64 B/thread, fully coalesced
    char* ft = feat + (long)nb * 32768;
#pragma unroll
    for (int j = 0; j < 4; ++j) {
        const int off = tid * 16 + j * 8192;
        *(uint4*)(ft + off) = *(const uint4*)(lds + off);
    }
}

// ---------------- K2: DMA dw-feat + raw staging + GEMM + epilogue ----------------
// LDS: [0,32K) dw region [64px][512B]; [32K,64K) raw region [64px][512B]; same swizzle.
__global__ __launch_bounds__(512, 4)
void gemm_kernel(const float* __restrict__ x, const char* __restrict__ feat,
                 const float* __restrict__ wts, const int* __restrict__ idx,
                 const unsigned short* __restrict__ wf0,
                 const unsigned short* __restrict__ wf1,
                 const unsigned short* __restrict__ wf2,
                 const float* __restrict__ beta,
                 float* __restrict__ out) {
    __shared__ __align__(16) char lds[64 * 1024];

    const int tid  = threadIdx.x;
    const int wave = tid >> 6;
    const int lane = tid & 63;

    const int bid = blockIdx.x;
    const int nb  = ((bid & 7) << 8) | (bid >> 3);
    const int b   = nb >> 6;
    const int h   = nb & 63;

    // ---- async DMA of dw feat tile (32 KB = 32 chunks of 1 KB; 4 per wave) ----
    const char* ft = feat + (long)nb * 32768;
#pragma unroll
    for (int j = 0; j < 4; ++j) {
        const int chunk = wave * 4 + j;
        gld_lds16(ft + chunk * 1024 + lane * 16, lds + chunk * 1024);
    }

    // per-batch expert coefficients
    float c0 = 0.f, c1 = 0.f, c2 = 0.f;
#pragma unroll
    for (int t = 0; t < 2; ++t) {
        int e = idx[b * 2 + t];
        float w = wts[b * 2 + t];
        if (e == 0) c0 += w;
        else if (e == 1) c1 += w;
        else if (e == 2) c2 += w;
    }
    const float cc[3] = {c0, c1, c2};

    const long rowBase = (long)b * 1048576L;

    // ---- raw staging: center-row x -> raw region (overlaps DMA) ----
    {
        const int g   = lane >> 2;
        const int kq  = lane & 3;
        const int px0 = g * 4;
        const int cb  = wave * 32 + kq * 8;          // 8 ch
        const float* xb = x + rowBase + h * 64 + px0;
        float4 r[8];
#pragma unroll
        for (int c = 0; c < 8; ++c)
            r[c] = *(const float4*)(xb + (long)(cb + c) * 4096);
        const int colb = (cb >> 3) * 16;
#pragma unroll
        for (int j = 0; j < 4; ++j) {
            const int px = px0 + j;
            float v0 = (j == 0) ? r[0].x : (j == 1) ? r[0].y : (j == 2) ? r[0].z : r[0].w;
            float v1 = (j == 0) ? r[1].x : (j == 1) ? r[1].y : (j == 2) ? r[1].z : r[1].w;
            float v2 = (j == 0) ? r[2].x : (j == 1) ? r[2].y : (j == 2) ? r[2].z : r[2].w;
            float v3 = (j == 0) ? r[3].x : (j == 1) ? r[3].y : (j == 2) ? r[3].z : r[3].w;
            float v4 = (j == 0) ? r[4].x : (j == 1) ? r[4].y : (j == 2) ? r[4].z : r[4].w;
            float v5 = (j == 0) ? r[5].x : (j == 1) ? r[5].y : (j == 2) ? r[5].z : r[5].w;
            float v6 = (j == 0) ? r[6].x : (j == 1) ? r[6].y : (j == 2) ? r[6].z : r[6].w;
            float v7 = (j == 0) ? r[7].x : (j == 1) ? r[7].y : (j == 2) ? r[7].z : r[7].w;
            uint4 pkv = make_uint4(pk_bf16(v0, v1), pk_bf16(v2, v3), pk_bf16(v4, v5), pk_bf16(v6, v7));
            *(uint4*)(lds + 32768 + px * 512 + ((colb ^ ((px & 7) << 4)))) = pkv;
        }
    }
    __syncthreads();   // drains DMA (vmcnt) + ds_writes

    // ---- GEMM ----
    const int l15 = lane & 15;
    const int l4  = lane >> 4;

    f32x4 res[2][4];
#pragma unroll
    for (int ot = 0; ot < 2; ++ot)
#pragma unroll
        for (int tp = 0; tp < 4; ++tp)
            res[ot][tp] = (f32x4){0.f, 0.f, 0.f, 0.f};

    const unsigned short* Wp[3] = {wf0, wf1, wf2};
    const int KeA[3] = {128, 128, 256};
    const int rbA[3] = {0, 0, 32768};                // LDS region base
    const int qbA[3] = {0, 256, 0};                  // col byte base within region

    int pxv[4], swv[4];
#pragma unroll
    for (int tp = 0; tp < 4; ++tp) {
        pxv[tp] = tp * 16 + l15;
        swv[tp] = (pxv[tp] & 7) << 4;
    }

#pragma unroll
    for (int e = 0; e < 3; ++e) {
        const unsigned short* W = Wp[e];
        const int Ke = KeA[e];
        const int nk = Ke >> 5;
        const char* lb = lds + rbA[e];
        const int qb = qbA[e];

        f32x4 acc[2][4];
#pragma unroll
        for (int ot = 0; ot < 2; ++ot)
#pragma unroll
            for (int tp = 0; tp < 4; ++tp)
                acc[ot][tp] = (f32x4){0.f, 0.f, 0.f, 0.f};

        const unsigned short* wb = W + (wave * 32 + l15) * Ke + l4 * 8;

        bf16x8 aC[2], bC[4];
#pragma unroll
        for (int ot = 0; ot < 2; ++ot) aC[ot] = *(const bf16x8*)(wb + ot * 16 * Ke);
#pragma unroll
        for (int tp = 0; tp < 4; ++tp)
            bC[tp] = *(const bf16x8*)(lb + pxv[tp] * 512 + ((qb + l4 * 16) ^ swv[tp]));

#pragma unroll
        for (int kk = 0; kk < 8; ++kk) {
            if (kk >= nk) break;
            bf16x8 aN[2], bN[4];
            if (kk + 1 < nk) {
#pragma unroll
                for (int ot = 0; ot < 2; ++ot)
                    aN[ot] = *(const bf16x8*)(wb + ot * 16 * Ke + (kk + 1) * 32);
#pragma unroll
                for (int tp = 0; tp < 4; ++tp)
                    bN[tp] = *(const bf16x8*)(lb + pxv[tp] * 512 + ((qb + (kk + 1) * 64 + l4 * 16) ^ swv[tp]));
            }
#pragma unroll
            for (int ot = 0; ot < 2; ++ot)
#pragma unroll
                for (int tp = 0; tp < 4; ++tp)
                    acc[ot][tp] = __builtin_amdgcn_mfma_f32_16x16x32_bf16(aC[ot], bC[tp], acc[ot][tp], 0, 0, 0);
            if (kk + 1 < nk) {
#pragma unroll
                for (int ot = 0; ot < 2; ++ot) aC[ot] = aN[ot];
#pragma unroll
                for (int tp = 0; tp < 4; ++tp) bC[tp] = bN[tp];
            }
        }

        const float ce = cc[e];
        const float* bp = beta + e * 256;
#pragma unroll
        for (int ot = 0; ot < 2; ++ot) {
#pragma unroll
            for (int j = 0; j < 4; ++j) {
                int o = wave * 32 + ot * 16 + l4 * 4 + j;
                float bet = bp[o];
#pragma unroll
                for (int tp = 0; tp < 4; ++tp) {
                    float v = acc[ot][tp][j] + bet;
                    float sig = __builtin_amdgcn_rcpf(1.f + __expf(-v));
                    res[ot][tp][j] += ce * (v * sig);
                }
            }
        }
    }

    // ---- store: transpose through LDS, coalesced lines ----
    float* lds_f = (float*)lds;
    const long outB = rowBase + h * 64;
    __syncthreads();
#pragma unroll
    for (int r = 0; r < 2; ++r) {
        if ((wave >> 2) == r) {
#pragma unroll
            for (int ot = 0; ot < 2; ++ot)
#pragma unroll
                for (int j = 0; j < 4; ++j) {
                    int o = wave * 32 + ot * 16 + l4 * 4 + j;
#pragma unroll
                    for (int tp = 0; tp < 4; ++tp)
                        lds_f[(o & 127) * 68 + tp * 16 + l15] = res[ot][tp][j];
                }
        }
        __syncthreads();
        {
            const int row = tid >> 4;                 // 0..31
            const int col = (tid & 15) * 4;
#pragma unroll
            for (int rr = 0; rr < 4; ++rr) {
                int lr = row + rr * 32;               // 0..127
                float4 v = *(float4*)&lds_f[lr * 68 + col];
                *(float4*)(out + outB + (long)(r * 128 + lr) * 4096 + col) = v;
            }
        }
        __syncthreads();
    }
}

// ---------------- fallback: round-2 fused kernel (used if ws too small) ----------------
__global__ __launch_bounds__(512, 4)
void fused_fallback(const float* __restrict__ x,
                    const float* __restrict__ wts, const int* __restrict__ idx,
                    const float* __restrict__ dw0, const float* __restrict__ dw1,
                    const unsigned short* __restrict__ wf0,
                    const unsigned short* __restrict__ wf1,
                    const unsigned short* __restrict__ wf2,
                    const float* __restrict__ beta,
                    float* __restrict__ out) {
    __shared__ __align__(16) char lds[64 * 1024];

    const int tid  = threadIdx.x;
    const int wave = tid >> 6;
    const int lane = tid & 63;

    const int bid = blockIdx.x;
    const int nb  = ((bid & 7) << 8) | (bid >> 3);
    const int b   = nb >> 6;
    const int h   = nb & 63;

    float c0 = 0.f, c1 = 0.f, c2 = 0.f;
#pragma unroll
    for (int t = 0; t < 2; ++t) {
        int e = idx[b * 2 + t];
        float w = wts[b * 2 + t];
        if (e == 0) c0 += w;
        else if (e == 1) c1 += w;
        else if (e == 2) c2 += w;
    }
    const float cc[3] = {c0, c1, c2};

    const long rowBase = (long)b * 1048576L;

    {
        const int g   = lane >> 2;
        const int kq  = lane & 3;
        const int px0 = g * 4;
        const float* xb = x + rowBase + h * 64 + px0;
        const bool hm = (h > 0), hp = (h < 63);

#pragma unroll
        for (int i = 0; i < 2; ++i) {
            const int k0 = wave * 32 + i * 16 + kq * 4;
            unsigned dw_p[2][4], rw_p[2][4];
#pragma unroll
            for (int pr = 0; pr < 2; ++pr) {
                float y[2][4]; float rv[2][4];
#pragma unroll
                for (int k2 = 0; k2 < 2; ++k2) {
                    const int k = k0 + pr * 2 + k2;
                    const float* dwp = (k < 128) ? (dw0 + k * 9) : (dw1 + (k - 128) * 9);
                    const float* xc = xb + (long)k * 4096;
                    float4 rm = hm ? *(const float4*)(xc - 64) : make_float4(0.f, 0.f, 0.f, 0.f);
                    float4 rc = *(const float4*)(xc);
                    float4 rp = hp ? *(const float4*)(xc + 64) : make_float4(0.f, 0.f, 0.f, 0.f);
                    float lm = __shfl_up(rm.w, 4), lc = __shfl_up(rc.w, 4), lp = __shfl_up(rp.w, 4);
                    float Rm = __shfl_down(rm.x, 4), Rc = __shfl_down(rc.x, 4), Rp = __shfl_down(rp.x, 4);
                    if (g == 0)  { lm = 0.f; lc = 0.f; lp = 0.f; }
                    if (g == 15) { Rm = 0.f; Rc = 0.f; Rp = 0.f; }
                    const float w0 = dwp[0], w1 = dwp[1], w2 = dwp[2];
                    const float w3 = dwp[3], w4 = dwp[4], w5 = dwp[5];
                    const float w6 = dwp[6], w7 = dwp[7], w8 = dwp[8];
                    y[k2][0] = w0*lm   + w1*rm.x + w2*rm.y + w3*lc   + w4*rc.x + w5*rc.y + w6*lp   + w7*rp.x + w8*rp.y;
                    y[k2][1] = w0*rm.x + w1*rm.y + w2*rm.z + w3*rc.x + w4*rc.y + w5*rc.z + w6*rp.x + w7*rp.y + w8*rp.z;
                    y[k2][2] = w0*rm.y + w1*rm.z + w2*rm.w + w3*rc.y + w4*rc.z + w5*rc.w + w6*rp.y + w7*rp.z + w8*rp.w;
                    y[k2][3] = w0*rm.z + w1*rm.w + w2*Rm   + w3*rc.z + w4*rc.w + w5*Rc   + w6*rp.z + w7*rp.w + w8*Rp;
                    rv[k2][0] = rc.x; rv[k2][1] = rc.y; rv[k2][2] = rc.z; rv[k2][3] = rc.w;
                }
#pragma unroll
                for (int j = 0; j < 4; ++j) {
                    dw_p[pr][j] = pk_bf16(y[0][j], y[1][j]);
                    rw_p[pr][j] = pk_bf16(rv[0][j], rv[1][j]);
                }
            }
            const int qd  = (k0 >> 3) * 16;
            const int qr  = qd + 32 * 16;
            const int sub = (k0 & 4) * 2;
#pragma unroll
            for (int j = 0; j < 4; ++j) {
                const int px = px0 + j;
                const int sw = (px & 7) << 4;
                *(uint2*)(lds + px * 1024 + (qd ^ sw) + sub) = make_uint2(dw_p[0][j], dw_p[1][j]);
                *(uint2*)(lds + px * 1024 + (qr ^ sw) + sub) = make_uint2(rw_p[0][j], rw_p[1][j]);
            }
        }
    }

    const int l15 = lane & 15;
    const int l4  = lane >> 4;
    bf16x8 pre0[2];
#pragma unroll
    for (int ot = 0; ot < 2; ++ot)
        pre0[ot] = *(const bf16x8*)(wf0 + (wave * 32 + ot * 16 + l15) * 128 + l4 * 8);

    __syncthreads();

    f32x4 res[2][4];
#pragma unroll
    for (int ot = 0; ot < 2; ++ot)
#pragma unroll
        for (int tp = 0; tp < 4; ++tp)
            res[ot][tp] = (f32x4){0.f, 0.f, 0.f, 0.f};

    const unsigned short* Wp[3] = {wf0, wf1, wf2};
    const int KeA[3] = {128, 128, 256};
    const int kbA[3] = {0, 128, 256};

    int pxv[4], swv[4];
#pragma unroll
    for (int tp = 0; tp < 4; ++tp) {
        pxv[tp] = tp * 16 + l15;
        swv[tp] = (pxv[tp] & 7) << 4;
    }

#pragma unroll
    for (int e = 0; e < 3; ++e) {
        const unsigned short* W = Wp[e];
        const int Ke = KeA[e];
        const int nk = Ke >> 5;
        const int qb = (kbA[e] >> 3) * 16;

        f32x4 acc[2][4];
#pragma unroll
        for (int ot = 0; ot < 2; ++ot)
#pragma unroll
            for (int tp = 0; tp < 4; ++tp)
                acc[ot][tp] = (f32x4){0.f, 0.f, 0.f, 0.f};

        const unsigned short* wb = W + (wave * 32 + l15) * Ke + l4 * 8;

        bf16x8 aC[2], bC[4];
        if (e == 0) { aC[0] = pre0[0]; aC[1] = pre0[1]; }
        else {
#pragma unroll
            for (int ot = 0; ot < 2; ++ot) aC[ot] = *(const bf16x8*)(wb + ot * 16 * Ke);
        }
#pragma unroll
        for (int tp = 0; tp < 4; ++tp)
            bC[tp] = *(const bf16x8*)(lds + pxv[tp] * 1024 + ((qb + l4 * 16) ^ swv[tp]));

#pragma unroll
        for (int kk = 0; kk < 8; ++kk) {
            if (kk >= nk) break;
            bf16x8 aN[2], bN[4];
            if (kk + 1 < nk) {
#pragma unroll
                for (int ot = 0; ot < 2; ++ot)
                    aN[ot] = *(const bf16x8*)(wb + ot * 16 * Ke + (kk + 1) * 32);
#pragma unroll
                for (int tp = 0; tp < 4; ++tp)
                    bN[tp] = *(const bf16x8*)(lds + pxv[tp] * 1024 + ((qb + (kk + 1) * 64 + l4 * 16) ^ swv[tp]));
            }
#pragma unroll
            for (int ot = 0; ot < 2; ++ot)
#pragma unroll
                for (int tp = 0; tp < 4; ++tp)
                    acc[ot][tp] = __builtin_amdgcn_mfma_f32_16x16x32_bf16(aC[ot], bC[tp], acc[ot][tp], 0, 0, 0);
            if (kk + 1 < nk) {
#pragma unroll
                for (int ot = 0; ot < 2; ++ot) aC[ot] = aN[ot];
#pragma unroll
                for (int tp = 0; tp < 4; ++tp) bC[tp] = bN[tp];
            }
        }

        const float ce = cc[e];
        const float* bp = beta + e * 256;
#pragma unroll
        for (int ot = 0; ot < 2; ++ot) {
#pragma unroll
            for (int j = 0; j < 4; ++j) {
                int o = wave * 32 + ot * 16 + l4 * 4 + j;
                float bet = bp[o];
#pragma unroll
                for (int tp = 0; tp < 4; ++tp) {
                    float v = acc[ot][tp][j] + bet;
                    float sig = __builtin_amdgcn_rcpf(1.f + __expf(-v));
                    res[ot][tp][j] += ce * (v * sig);
                }
            }
        }
    }

    float* lds_f = (float*)lds;
    const long outB = rowBase + h * 64;
    __syncthreads();
#pragma unroll
    for (int r = 0; r < 2; ++r) {
        if ((wave >> 2) == r) {
#pragma unroll
            for (int ot = 0; ot < 2; ++ot)
#pragma unroll
                for (int j = 0; j < 4; ++j) {
                    int o = wave * 32 + ot * 16 + l4 * 4 + j;
#pragma unroll
                    for (int tp = 0; tp < 4; ++tp)
                        lds_f[(o & 127) * 68 + tp * 16 + l15] = res[ot][tp][j];
                }
        }
        __syncthreads();
        {
            const int row = tid >> 4;
            const int col = (tid & 15) * 4;
#pragma unroll
            for (int rr = 0; rr < 4; ++rr) {
                int lr = row + rr * 32;
                float4 v = *(float4*)&lds_f[lr * 68 + col];
                *(float4*)(out + outB + (long)(r * 128 + lr) * 4096 + col) = v;
            }
        }
        __syncthreads();
    }
}

extern "C" void kernel_launch(void* const* d_in, const int* in_sizes, int n_in,
                              void* d_out, int out_size, void* d_ws, size_t ws_size,
                              hipStream_t stream) {
    const float* x    = (const float*)d_in[0];
    const float* wts  = (const float*)d_in[1];
    const int*   idx  = (const int*)d_in[2];
    const float* dw0  = (const float*)d_in[3];
    const float* pw0  = (const float*)d_in[4];
    const float* s0   = (const float*)d_in[5];
    const float* b0   = (const float*)d_in[6];
    const float* m0   = (const float*)d_in[7];
    const float* v0   = (const float*)d_in[8];
    const float* dw1  = (const float*)d_in[9];
    const float* pw1  = (const float*)d_in[10];
    const float* s1   = (const float*)d_in[11];
    const float* b1   = (const float*)d_in[12];
    const float* m1   = (const float*)d_in[13];
    const float* v1   = (const float*)d_in[14];
    const float* w2   = (const float*)d_in[15];
    const float* s2   = (const float*)d_in[16];
    const float* b2   = (const float*)d_in[17];
    const float* m2   = (const float*)d_in[18];
    const float* v2   = (const float*)d_in[19];

    char* ws = (char*)d_ws;
    unsigned short* wf0  = (unsigned short*)ws;                 // 64 KB
    unsigned short* wf1  = (unsigned short*)(ws + 65536);       // 64 KB
    unsigned short* wf2  = (unsigned short*)(ws + 131072);      // 128 KB
    float*          beta = (float*)(ws + 262144);               // 3 KB
    char*           feat = ws + 524288;                         // 64 MB

    const size_t need = 524288ull + 2048ull * 32768ull;

    prep_kernel<<<256, 256, 0, stream>>>(pw0, pw1, w2,
                                         s0, b0, m0, v0,
                                         s1, b1, m1, v1,
                                         s2, b2, m2, v2,
                                         wf0, wf1, wf2, beta);

    if (ws_size >= need) {
        dw_stage_kernel<<<2048, 512, 0, stream>>>(x, dw0, dw1, feat);
        gemm_kernel<<<2048, 512, 0, stream>>>(x, feat, wts, idx,
                                              wf0, wf1, wf2, beta, (float*)d_out);
    } else {
        fused_fallback<<<2048, 512, 0, stream>>>(x, wts, idx, dw0, dw1,
                                                 wf0, wf1, wf2, beta, (float*)d_out);
    }
}

// Round 5
// 193.236 us; speedup vs baseline: 1.2116x; 1.1475x over previous
//
#include <hip/hip_runtime.h>

typedef __bf16 bf16x8 __attribute__((ext_vector_type(8)));
typedef float f32x4 __attribute__((ext_vector_type(4)));

#define BN_EPS 1e-5f

__device__ __forceinline__ unsigned short f2bf(float f) {
    union { float f; unsigned u; } x; x.f = f;
    unsigned r = x.u + 0x7fffu + ((x.u >> 16) & 1u);
    return (unsigned short)(r >> 16);
}

__device__ __forceinline__ unsigned pk_bf16(float lo, float hi) {
    unsigned r;
    asm("v_cvt_pk_bf16_f32 %0, %1, %2" : "=v"(r) : "v"(lo), "v"(hi));
    return r;
}

// ---------------- prepass: fold BN scale into weights, FRAGMENT-CONTIGUOUS layout ----
// wfF[e]: for koct q = k/8, outch o: frag at ((q*256 + o)*8 + (k&7)), bf16.
// A-load for (row, koct) is then 16 B at (koct*256 + row)*16 bytes: lanes with
// consecutive row (l15) are contiguous 256-B runs -> ~8 L2 line-requests/instr.
__global__ void prep_kernel(const float* __restrict__ pw0, const float* __restrict__ pw1,
                            const float* __restrict__ w2,
                            const float* __restrict__ s0, const float* __restrict__ b0,
                            const float* __restrict__ m0, const float* __restrict__ v0,
                            const float* __restrict__ s1, const float* __restrict__ b1,
                            const float* __restrict__ m1, const float* __restrict__ v1,
                            const float* __restrict__ s2, const float* __restrict__ b2,
                            const float* __restrict__ m2, const float* __restrict__ v2,
                            unsigned short* __restrict__ wfF0, unsigned short* __restrict__ wfF1,
                            unsigned short* __restrict__ wfF2, float* __restrict__ beta) {
    int o = blockIdx.x;     // 0..255 outch
    int t = threadIdx.x;    // 0..255 k
    float inv0 = s0[o] * rsqrtf(v0[o] + BN_EPS);
    float inv1 = s1[o] * rsqrtf(v1[o] + BN_EPS);
    float inv2 = s2[o] * rsqrtf(v2[o] + BN_EPS);
    if (t == 0) {
        beta[0 * 256 + o] = b0[o] - m0[o] * inv0;
        beta[1 * 256 + o] = b1[o] - m1[o] * inv1;
        beta[2 * 256 + o] = b2[o] - m2[o] * inv2;
    }
    if (t < 128) {
        wfF0[((t >> 3) * 256 + o) * 8 + (t & 7)] = f2bf(pw0[o * 128 + t] * inv0);
        wfF1[((t >> 3) * 256 + o) * 8 + (t & 7)] = f2bf(pw1[o * 128 + t] * inv1);
    }
    wfF2[((t >> 3) * 256 + o) * 8 + (t & 7)] = f2bf(w2[o * 256 + t] * inv2);
}

// ---------------- main fused kernel: 1 WG per (b,h) row, 8 waves ----------------------
// LDS B-tile: [64 px][512 K] bf16, px-major (1024 B/px), 16-B cols swizzled ^((px&7)<<4).
// K layout: [0,128)=dw(rgb), [128,256)=dw(ir), [256,512)=raw x.
__global__ __launch_bounds__(512, 4)
void fused_kernel(const float* __restrict__ x,
                  const float* __restrict__ wts, const int* __restrict__ idx,
                  const float* __restrict__ dw0, const float* __restrict__ dw1,
                  const unsigned short* __restrict__ wfF0,
                  const unsigned short* __restrict__ wfF1,
                  const unsigned short* __restrict__ wfF2,
                  const float* __restrict__ beta,
                  float* __restrict__ out) {
    __shared__ __align__(16) char lds[64 * 1024];

    const int tid  = threadIdx.x;
    const int wave = tid >> 6;
    const int lane = tid & 63;

    const int bid = blockIdx.x;
    const int nb  = ((bid & 7) << 8) | (bid >> 3);   // XCD swizzle, bijective on 2048
    const int b   = nb >> 6;
    const int h   = nb & 63;

    float c0 = 0.f, c1 = 0.f, c2 = 0.f;
#pragma unroll
    for (int t = 0; t < 2; ++t) {
        int e = idx[b * 2 + t];
        float w = wts[b * 2 + t];
        if (e == 0) c0 += w;
        else if (e == 1) c1 += w;
        else if (e == 2) c2 += w;
    }
    const float cc[3] = {c0, c1, c2};

    const long rowBase = (long)b * 1048576L;

    const int l15 = lane & 15;
    const int l4  = lane >> 4;

    // ---------- stage LDS (depthwise + raw merged; proven round-2 code) ----------
    {
        const int g   = lane >> 2;
        const int kq  = lane & 3;
        const int px0 = g * 4;
        const float* xb = x + rowBase + h * 64 + px0;
        const bool hm = (h > 0), hp = (h < 63);

#pragma unroll
        for (int i = 0; i < 2; ++i) {
            const int k0 = wave * 32 + i * 16 + kq * 4;
            unsigned dw_p[2][4], rw_p[2][4];
#pragma unroll
            for (int pr = 0; pr < 2; ++pr) {
                float y[2][4]; float rv[2][4];
#pragma unroll
                for (int k2 = 0; k2 < 2; ++k2) {
                    const int k = k0 + pr * 2 + k2;
                    const float* dwp = (k < 128) ? (dw0 + k * 9) : (dw1 + (k - 128) * 9);
                    const float* xc = xb + (long)k * 4096;
                    float4 rm = hm ? *(const float4*)(xc - 64) : make_float4(0.f, 0.f, 0.f, 0.f);
                    float4 rc = *(const float4*)(xc);
                    float4 rp = hp ? *(const float4*)(xc + 64) : make_float4(0.f, 0.f, 0.f, 0.f);
                    float lm = __shfl_up(rm.w, 4), lc = __shfl_up(rc.w, 4), lp = __shfl_up(rp.w, 4);
                    float Rm = __shfl_down(rm.x, 4), Rc = __shfl_down(rc.x, 4), Rp = __shfl_down(rp.x, 4);
                    if (g == 0)  { lm = 0.f; lc = 0.f; lp = 0.f; }
                    if (g == 15) { Rm = 0.f; Rc = 0.f; Rp = 0.f; }
                    const float w0 = dwp[0], w1 = dwp[1], w2 = dwp[2];
                    const float w3 = dwp[3], w4 = dwp[4], w5 = dwp[5];
                    const float w6 = dwp[6], w7 = dwp[7], w8 = dwp[8];
                    y[k2][0] = w0*lm   + w1*rm.x + w2*rm.y + w3*lc   + w4*rc.x + w5*rc.y + w6*lp   + w7*rp.x + w8*rp.y;
                    y[k2][1] = w0*rm.x + w1*rm.y + w2*rm.z + w3*rc.x + w4*rc.y + w5*rc.z + w6*rp.x + w7*rp.y + w8*rp.z;
                    y[k2][2] = w0*rm.y + w1*rm.z + w2*rm.w + w3*rc.y + w4*rc.z + w5*rc.w + w6*rp.y + w7*rp.z + w8*rp.w;
                    y[k2][3] = w0*rm.z + w1*rm.w + w2*Rm   + w3*rc.z + w4*rc.w + w5*Rc   + w6*rp.z + w7*rp.w + w8*Rp;
                    rv[k2][0] = rc.x; rv[k2][1] = rc.y; rv[k2][2] = rc.z; rv[k2][3] = rc.w;
                }
#pragma unroll
                for (int j = 0; j < 4; ++j) {
                    dw_p[pr][j] = pk_bf16(y[0][j], y[1][j]);
                    rw_p[pr][j] = pk_bf16(rv[0][j], rv[1][j]);
                }
            }
            const int qd  = (k0 >> 3) * 16;
            const int qr  = qd + 32 * 16;
            const int sub = (k0 & 4) * 2;
#pragma unroll
            for (int j = 0; j < 4; ++j) {
                const int px = px0 + j;
                const int sw = (px & 7) << 4;
                *(uint2*)(lds + px * 1024 + (qd ^ sw) + sub) = make_uint2(dw_p[0][j], dw_p[1][j]);
                *(uint2*)(lds + px * 1024 + (qr ^ sw) + sub) = make_uint2(rw_p[0][j], rw_p[1][j]);
            }
        }
    }

    // prefetch e=0 / ot=0 A-burst before the barrier (independent of LDS)
    bf16x8 pre[4];
#pragma unroll
    for (int j = 0; j < 4; ++j)
        pre[j] = *(const bf16x8*)(wfF0 + ((j * 4 + l4) * 256 + wave * 32 + l15) * 8);

    __syncthreads();

    // ---------- GEMM phases ----------
    f32x4 res[2][4];
#pragma unroll
    for (int ot = 0; ot < 2; ++ot)
#pragma unroll
        for (int tp = 0; tp < 4; ++tp)
            res[ot][tp] = (f32x4){0.f, 0.f, 0.f, 0.f};

    const unsigned short* WF[3] = {wfF0, wfF1, wfF2};
    const int nkA[3] = {4, 4, 8};
    const int qbA[3] = {0, 256, 512};                // LDS byte col base

    int pxv[4], swv[4];
#pragma unroll
    for (int tp = 0; tp < 4; ++tp) {
        pxv[tp] = tp * 16 + l15;
        swv[tp] = (pxv[tp] & 7) << 4;
    }

#pragma unroll
    for (int e = 0; e < 3; ++e) {
        const unsigned short* W = WF[e];
        const int nk = nkA[e];
        const int qb = qbA[e];

        f32x4 acc[2][4];
#pragma unroll
        for (int ot = 0; ot < 2; ++ot)
#pragma unroll
            for (int tp = 0; tp < 4; ++tp)
                acc[ot][tp] = (f32x4){0.f, 0.f, 0.f, 0.f};

#pragma unroll
        for (int ot = 0; ot < 2; ++ot) {
            const int row = wave * 32 + ot * 16 + l15;
#pragma unroll
            for (int ck = 0; ck < 2; ++ck) {
                if (ck * 4 >= nk) break;
                // A-burst: 4 fragments (16 VGPRs), one independent L2 round-trip
                bf16x8 af[4];
                if (e == 0 && ot == 0 && ck == 0) {
#pragma unroll
                    for (int j = 0; j < 4; ++j) af[j] = pre[j];
                } else {
#pragma unroll
                    for (int j = 0; j < 4; ++j)
                        af[j] = *(const bf16x8*)(W + (((ck * 4 + j) * 4 + l4) * 256 + row) * 8);
                }
#pragma unroll
                for (int j = 0; j < 4; ++j) {
                    const int kk = ck * 4 + j;
                    bf16x8 bb[4];
#pragma unroll
                    for (int tp = 0; tp < 4; ++tp)
                        bb[tp] = *(const bf16x8*)(lds + pxv[tp] * 1024 + ((qb + kk * 64 + l4 * 16) ^ swv[tp]));
#pragma unroll
                    for (int tp = 0; tp < 4; ++tp)
                        acc[ot][tp] = __builtin_amdgcn_mfma_f32_16x16x32_bf16(af[j], bb[tp], acc[ot][tp], 0, 0, 0);
                }
            }
        }

        // epilogue: BN shift + SiLU + weighted accumulate
        const float ce = cc[e];
        const float* bp = beta + e * 256;
#pragma unroll
        for (int ot = 0; ot < 2; ++ot) {
#pragma unroll
            for (int j = 0; j < 4; ++j) {
                int o = wave * 32 + ot * 16 + l4 * 4 + j;
                float bet = bp[o];
#pragma unroll
                for (int tp = 0; tp < 4; ++tp) {
                    float v = acc[ot][tp][j] + bet;
                    float sig = __builtin_amdgcn_rcpf(1.f + __expf(-v));
                    res[ot][tp][j] += ce * (v * sig);
                }
            }
        }
    }

    // ---------- store: transpose through LDS, coalesced 256-B lines ----------
    float* lds_f = (float*)lds;
    const long outB = rowBase + h * 64;
    __syncthreads();
#pragma unroll
    for (int r = 0; r < 2; ++r) {
        if ((wave >> 2) == r) {
#pragma unroll
            for (int ot = 0; ot < 2; ++ot)
#pragma unroll
                for (int j = 0; j < 4; ++j) {
                    int o = wave * 32 + ot * 16 + l4 * 4 + j;
#pragma unroll
                    for (int tp = 0; tp < 4; ++tp)
                        lds_f[(o & 127) * 68 + tp * 16 + l15] = res[ot][tp][j];
                }
        }
        __syncthreads();
        {
            const int row = tid >> 4;                 // 0..31
            const int col = (tid & 15) * 4;
#pragma unroll
            for (int rr = 0; rr < 4; ++rr) {
                int lr = row + rr * 32;               // 0..127
                float4 v = *(float4*)&lds_f[lr * 68 + col];
                *(float4*)(out + outB + (long)(r * 128 + lr) * 4096 + col) = v;
            }
        }
        __syncthreads();
    }
}

extern "C" void kernel_launch(void* const* d_in, const int* in_sizes, int n_in,
                              void* d_out, int out_size, void* d_ws, size_t ws_size,
                              hipStream_t stream) {
    const float* x    = (const float*)d_in[0];
    const float* wts  = (const float*)d_in[1];
    const int*   idx  = (const int*)d_in[2];
    const float* dw0  = (const float*)d_in[3];
    const float* pw0  = (const float*)d_in[4];
    const float* s0   = (const float*)d_in[5];
    const float* b0   = (const float*)d_in[6];
    const float* m0   = (const float*)d_in[7];
    const float* v0   = (const float*)d_in[8];
    const float* dw1  = (const float*)d_in[9];
    const float* pw1  = (const float*)d_in[10];
    const float* s1   = (const float*)d_in[11];
    const float* b1   = (const float*)d_in[12];
    const float* m1   = (const float*)d_in[13];
    const float* v1   = (const float*)d_in[14];
    const float* w2   = (const float*)d_in[15];
    const float* s2   = (const float*)d_in[16];
    const float* b2   = (const float*)d_in[17];
    const float* m2   = (const float*)d_in[18];
    const float* v2   = (const float*)d_in[19];

    char* ws = (char*)d_ws;
    unsigned short* wfF0 = (unsigned short*)ws;                 // 64 KB
    unsigned short* wfF1 = (unsigned short*)(ws + 65536);       // 64 KB
    unsigned short* wfF2 = (unsigned short*)(ws + 131072);      // 128 KB
    float*          beta = (float*)(ws + 262144);               // 3 KB

    prep_kernel<<<256, 256, 0, stream>>>(pw0, pw1, w2,
                                         s0, b0, m0, v0,
                                         s1, b1, m1, v1,
                                         s2, b2, m2, v2,
                                         wfF0, wfF1, wfF2, beta);

    fused_kernel<<<2048, 512, 0, stream>>>(x, wts, idx, dw0, dw1,
                                           wfF0, wfF1, wfF2, beta, (float*)d_out);
}

// Round 6
// 177.599 us; speedup vs baseline: 1.3183x; 1.0880x over previous
//
#include <hip/hip_runtime.h>

typedef __bf16 bf16x8 __attribute__((ext_vector_type(8)));
typedef float f32x4 __attribute__((ext_vector_type(4)));

#define BN_EPS 1e-5f

__device__ __forceinline__ unsigned short f2bf(float f) {
    union { float f; unsigned u; } x; x.f = f;
    unsigned r = x.u + 0x7fffu + ((x.u >> 16) & 1u);
    return (unsigned short)(r >> 16);
}

__device__ __forceinline__ unsigned pk_bf16(float lo, float hi) {
    unsigned r;
    asm("v_cvt_pk_bf16_f32 %0, %1, %2" : "=v"(r) : "v"(lo), "v"(hi));
    return r;
}

// ---------------- prepass: fold BN scale into weights, FRAGMENT-CONTIGUOUS layout ----
// wfF[e]: frag for koct q=k/8, outch o at ((q*256 + o)*8 + (k&7)).
__global__ void prep_kernel(const float* __restrict__ pw0, const float* __restrict__ pw1,
                            const float* __restrict__ w2,
                            const float* __restrict__ s0, const float* __restrict__ b0,
                            const float* __restrict__ m0, const float* __restrict__ v0,
                            const float* __restrict__ s1, const float* __restrict__ b1,
                            const float* __restrict__ m1, const float* __restrict__ v1,
                            const float* __restrict__ s2, const float* __restrict__ b2,
                            const float* __restrict__ m2, const float* __restrict__ v2,
                            unsigned short* __restrict__ wfF0, unsigned short* __restrict__ wfF1,
                            unsigned short* __restrict__ wfF2, float* __restrict__ beta) {
    int o = blockIdx.x;     // 0..255 outch
    int t = threadIdx.x;    // 0..255 k
    float inv0 = s0[o] * rsqrtf(v0[o] + BN_EPS);
    float inv1 = s1[o] * rsqrtf(v1[o] + BN_EPS);
    float inv2 = s2[o] * rsqrtf(v2[o] + BN_EPS);
    if (t == 0) {
        beta[0 * 256 + o] = b0[o] - m0[o] * inv0;
        beta[1 * 256 + o] = b1[o] - m1[o] * inv1;
        beta[2 * 256 + o] = b2[o] - m2[o] * inv2;
    }
    if (t < 128) {
        wfF0[((t >> 3) * 256 + o) * 8 + (t & 7)] = f2bf(pw0[o * 128 + t] * inv0);
        wfF1[((t >> 3) * 256 + o) * 8 + (t & 7)] = f2bf(pw1[o * 128 + t] * inv1);
    }
    wfF2[((t >> 3) * 256 + o) * 8 + (t & 7)] = f2bf(w2[o * 256 + t] * inv2);
}

// ---------------- GEMM helper: r2 structure (kk-outer, depth-1 prefetch) --------------
// B-tile: [64 px][256 K] bf16, px-major 512 B/px, 16-B col c stored at c ^ (px&15).
template<int NK>
__device__ __forceinline__ void gemm_expert(const char* lds, const unsigned short* __restrict__ W,
                                            int qb, int wave, int l15, int l4,
                                            const int* pxv, const int* swv, f32x4 acc[2][4]) {
    const int row0 = wave * 32 + l15;
    bf16x8 aC[2], bC[4];
#pragma unroll
    for (int ot = 0; ot < 2; ++ot)
        aC[ot] = *(const bf16x8*)(W + (l4 * 256 + row0 + ot * 16) * 8);
#pragma unroll
    for (int tp = 0; tp < 4; ++tp)
        bC[tp] = *(const bf16x8*)(lds + pxv[tp] * 512 + ((qb + l4 * 16) ^ swv[tp]));

#pragma unroll
    for (int kk = 0; kk < NK; ++kk) {
        bf16x8 aN[2], bN[4];
        if (kk + 1 < NK) {
#pragma unroll
            for (int ot = 0; ot < 2; ++ot)
                aN[ot] = *(const bf16x8*)(W + (((kk + 1) * 4 + l4) * 256 + row0 + ot * 16) * 8);
#pragma unroll
            for (int tp = 0; tp < 4; ++tp)
                bN[tp] = *(const bf16x8*)(lds + pxv[tp] * 512 + ((qb + (kk + 1) * 64 + l4 * 16) ^ swv[tp]));
        }
#pragma unroll
        for (int ot = 0; ot < 2; ++ot)
#pragma unroll
            for (int tp = 0; tp < 4; ++tp)
                acc[ot][tp] = __builtin_amdgcn_mfma_f32_16x16x32_bf16(aC[ot], bC[tp], acc[ot][tp], 0, 0, 0);
        if (kk + 1 < NK) {
#pragma unroll
            for (int ot = 0; ot < 2; ++ot) aC[ot] = aN[ot];
#pragma unroll
            for (int tp = 0; tp < 4; ++tp) bC[tp] = bN[tp];
        }
    }
}

__device__ __forceinline__ void epilogue(const f32x4 acc[2][4], float ce, const float* __restrict__ bp,
                                         int wave, int l4, f32x4 res[2][4]) {
#pragma unroll
    for (int ot = 0; ot < 2; ++ot)
#pragma unroll
        for (int j = 0; j < 4; ++j) {
            const int o = wave * 32 + ot * 16 + l4 * 4 + j;
            const float bet = bp[o];
#pragma unroll
            for (int tp = 0; tp < 4; ++tp) {
                float v = acc[ot][tp][j] + bet;
                float sig = __builtin_amdgcn_rcpf(1.f + __expf(-v));
                res[ot][tp][j] += ce * (v * sig);
            }
        }
}

// ---------------- main fused kernel: 1 WG per (b,h) row, 8 waves, 2 K-passes ----------
__global__ __launch_bounds__(512, 8)
void fused_kernel(const float* __restrict__ x,
                  const float* __restrict__ wts, const int* __restrict__ idx,
                  const float* __restrict__ dw0, const float* __restrict__ dw1,
                  const unsigned short* __restrict__ wfF0,
                  const unsigned short* __restrict__ wfF1,
                  const unsigned short* __restrict__ wfF2,
                  const float* __restrict__ beta,
                  float* __restrict__ out) {
    __shared__ __align__(16) char lds[34816];        // B-tile 32 KB; transpose 34.8 KB

    const int tid  = threadIdx.x;
    const int wave = tid >> 6;
    const int lane = tid & 63;

    const int bid = blockIdx.x;
    const int nb  = ((bid & 7) << 8) | (bid >> 3);   // XCD swizzle, bijective on 2048
    const int b   = nb >> 6;
    const int h   = nb & 63;

    float c0 = 0.f, c1 = 0.f, c2 = 0.f;
#pragma unroll
    for (int t = 0; t < 2; ++t) {
        int e = idx[b * 2 + t];
        float w = wts[b * 2 + t];
        if (e == 0) c0 += w;
        else if (e == 1) c1 += w;
        else if (e == 2) c2 += w;
    }
    const bool do0 = (c0 != 0.f), do1 = (c1 != 0.f), do2 = (c2 != 0.f);

    const long rowBase = (long)b * 1048576L;

    const int g   = lane >> 2;                       // px-group 0..15
    const int kq  = lane & 3;
    const int px0 = g * 4;
    const int l15 = lane & 15;
    const int l4  = lane >> 4;
    const float* xb = x + rowBase + h * 64 + px0;
    const bool hm = (h > 0), hp = (h < 63);

    f32x4 res[2][4];
#pragma unroll
    for (int ot = 0; ot < 2; ++ot)
#pragma unroll
        for (int tp = 0; tp < 4; ++tp)
            res[ot][tp] = (f32x4){0.f, 0.f, 0.f, 0.f};

    int pxv[4], swv[4];
#pragma unroll
    for (int tp = 0; tp < 4; ++tp) {
        pxv[tp] = tp * 16 + l15;
        swv[tp] = (pxv[tp] & 15) << 4;
    }

    // ================= pass 1: depthwise experts (K 0..255 = dw0 | dw1) ==============
    if (do0 || do1) {
        // waves 0-3 stage ch 0..127 (expert0), waves 4-7 stage ch 128..255 (expert1)
        if ((wave < 4) ? do0 : do1) {
#pragma unroll
            for (int i = 0; i < 2; ++i) {
                const int k0 = wave * 32 + i * 16 + kq * 4;
                unsigned dw_p[2][4];
#pragma unroll
                for (int pr = 0; pr < 2; ++pr) {
                    float y[2][4];
#pragma unroll
                    for (int k2 = 0; k2 < 2; ++k2) {
                        const int k = k0 + pr * 2 + k2;
                        const float* dwp = (k < 128) ? (dw0 + k * 9) : (dw1 + (k - 128) * 9);
                        const float* xc = xb + (long)k * 4096;
                        float4 rm = hm ? *(const float4*)(xc - 64) : make_float4(0.f, 0.f, 0.f, 0.f);
                        float4 rc = *(const float4*)(xc);
                        float4 rp = hp ? *(const float4*)(xc + 64) : make_float4(0.f, 0.f, 0.f, 0.f);
                        float lm = __shfl_up(rm.w, 4), lc = __shfl_up(rc.w, 4), lp = __shfl_up(rp.w, 4);
                        float Rm = __shfl_down(rm.x, 4), Rc = __shfl_down(rc.x, 4), Rp = __shfl_down(rp.x, 4);
                        if (g == 0)  { lm = 0.f; lc = 0.f; lp = 0.f; }
                        if (g == 15) { Rm = 0.f; Rc = 0.f; Rp = 0.f; }
                        const float w0 = dwp[0], w1 = dwp[1], w2 = dwp[2];
                        const float w3 = dwp[3], w4 = dwp[4], w5 = dwp[5];
                        const float w6 = dwp[6], w7 = dwp[7], w8 = dwp[8];
                        y[k2][0] = w0*lm   + w1*rm.x + w2*rm.y + w3*lc   + w4*rc.x + w5*rc.y + w6*lp   + w7*rp.x + w8*rp.y;
                        y[k2][1] = w0*rm.x + w1*rm.y + w2*rm.z + w3*rc.x + w4*rc.y + w5*rc.z + w6*rp.x + w7*rp.y + w8*rp.z;
                        y[k2][2] = w0*rm.y + w1*rm.z + w2*rm.w + w3*rc.y + w4*rc.z + w5*rc.w + w6*rp.y + w7*rp.z + w8*rp.w;
                        y[k2][3] = w0*rm.z + w1*rm.w + w2*Rm   + w3*rc.z + w4*rc.w + w5*Rc   + w6*rp.z + w7*rp.w + w8*Rp;
                    }
#pragma unroll
                    for (int j = 0; j < 4; ++j)
                        dw_p[pr][j] = pk_bf16(y[0][j], y[1][j]);
                }
                const int colb = (k0 >> 3) * 16;
                const int sub  = (k0 & 4) * 2;
#pragma unroll
                for (int j = 0; j < 4; ++j) {
                    const int px = px0 + j;
                    *(uint2*)(lds + px * 512 + ((colb ^ ((px & 15) << 4))) + sub) =
                        make_uint2(dw_p[0][j], dw_p[1][j]);
                }
            }
        }
        __syncthreads();
        if (do0) {
            f32x4 acc[2][4];
#pragma unroll
            for (int ot = 0; ot < 2; ++ot)
#pragma unroll
                for (int tp = 0; tp < 4; ++tp) acc[ot][tp] = (f32x4){0.f, 0.f, 0.f, 0.f};
            gemm_expert<4>(lds, wfF0, 0, wave, l15, l4, pxv, swv, acc);
            epilogue(acc, c0, beta, wave, l4, res);
        }
        if (do1) {
            f32x4 acc[2][4];
#pragma unroll
            for (int ot = 0; ot < 2; ++ot)
#pragma unroll
                for (int tp = 0; tp < 4; ++tp) acc[ot][tp] = (f32x4){0.f, 0.f, 0.f, 0.f};
            gemm_expert<4>(lds, wfF1, 256, wave, l15, l4, pxv, swv, acc);
            epilogue(acc, c1, beta + 256, wave, l4, res);
        }
    }

    // ================= pass 2: raw expert (K 0..255 = x channels) ====================
    if (do2) {
        __syncthreads();                             // pass-1 readers done before overwrite
        {
            const int cb = wave * 32 + kq * 8;       // 8 channels
            float4 r[8];
#pragma unroll
            for (int c = 0; c < 8; ++c)
                r[c] = *(const float4*)(xb + (long)(cb + c) * 4096);
            const int colb = (cb >> 3) * 16;
#pragma unroll
            for (int j = 0; j < 4; ++j) {
                const int px = px0 + j;
                float v0 = (j == 0) ? r[0].x : (j == 1) ? r[0].y : (j == 2) ? r[0].z : r[0].w;
                float v1 = (j == 0) ? r[1].x : (j == 1) ? r[1].y : (j == 2) ? r[1].z : r[1].w;
                float v2 = (j == 0) ? r[2].x : (j == 1) ? r[2].y : (j == 2) ? r[2].z : r[2].w;
                float v3 = (j == 0) ? r[3].x : (j == 1) ? r[3].y : (j == 2) ? r[3].z : r[3].w;
                float v4 = (j == 0) ? r[4].x : (j == 1) ? r[4].y : (j == 2) ? r[4].z : r[4].w;
                float v5 = (j == 0) ? r[5].x : (j == 1) ? r[5].y : (j == 2) ? r[5].z : r[5].w;
                float v6 = (j == 0) ? r[6].x : (j == 1) ? r[6].y : (j == 2) ? r[6].z : r[6].w;
                float v7 = (j == 0) ? r[7].x : (j == 1) ? r[7].y : (j == 2) ? r[7].z : r[7].w;
                *(uint4*)(lds + px * 512 + ((colb ^ ((px & 15) << 4)))) =
                    make_uint4(pk_bf16(v0, v1), pk_bf16(v2, v3), pk_bf16(v4, v5), pk_bf16(v6, v7));
            }
        }
        __syncthreads();
        {
            f32x4 acc[2][4];
#pragma unroll
            for (int ot = 0; ot < 2; ++ot)
#pragma unroll
                for (int tp = 0; tp < 4; ++tp) acc[ot][tp] = (f32x4){0.f, 0.f, 0.f, 0.f};
            gemm_expert<8>(lds, wfF2, 0, wave, l15, l4, pxv, swv, acc);
            epilogue(acc, c2, beta + 512, wave, l4, res);
        }
    }

    // ================= store: transpose through LDS, full-line writes ================
    float* lf = (float*)lds;
    const long outB = rowBase + h * 64;
    __syncthreads();
#pragma unroll
    for (int r = 0; r < 2; ++r) {
        if ((wave >> 2) == r) {
#pragma unroll
            for (int ot = 0; ot < 2; ++ot)
#pragma unroll
                for (int j = 0; j < 4; ++j) {
                    const int o = wave * 32 + ot * 16 + l4 * 4 + j;
#pragma unroll
                    for (int tp = 0; tp < 4; ++tp)
                        lf[(o & 127) * 68 + tp * 16 + l15] = res[ot][tp][j];
                }
        }
        __syncthreads();
        {
            const int rowq = tid >> 3;               // 0..63
            const int col  = (tid & 7) * 8;          // float index
#pragma unroll
            for (int rr = 0; rr < 2; ++rr) {
                const int lr = rowq + rr * 64;       // 0..127
                float4 v0 = *(float4*)&lf[lr * 68 + col];
                float4 v1 = *(float4*)&lf[lr * 68 + col + 4];
                float* op = out + outB + (long)(r * 128 + lr) * 4096 + col;
                *(float4*)op = v0;
                *(float4*)(op + 4) = v1;
            }
        }
        __syncthreads();
    }
}

extern "C" void kernel_launch(void* const* d_in, const int* in_sizes, int n_in,
                              void* d_out, int out_size, void* d_ws, size_t ws_size,
                              hipStream_t stream) {
    const float* x    = (const float*)d_in[0];
    const float* wts  = (const float*)d_in[1];
    const int*   idx  = (const int*)d_in[2];
    const float* dw0  = (const float*)d_in[3];
    const float* pw0  = (const float*)d_in[4];
    const float* s0   = (const float*)d_in[5];
    const float* b0   = (const float*)d_in[6];
    const float* m0   = (const float*)d_in[7];
    const float* v0   = (const float*)d_in[8];
    const float* dw1  = (const float*)d_in[9];
    const float* pw1  = (const float*)d_in[10];
    const float* s1   = (const float*)d_in[11];
    const float* b1   = (const float*)d_in[12];
    const float* m1   = (const float*)d_in[13];
    const float* v1   = (const float*)d_in[14];
    const float* w2   = (const float*)d_in[15];
    const float* s2   = (const float*)d_in[16];
    const float* b2   = (const float*)d_in[17];
    const float* m2   = (const float*)d_in[18];
    const float* v2   = (const float*)d_in[19];

    char* ws = (char*)d_ws;
    unsigned short* wfF0 = (unsigned short*)ws;                 // 64 KB
    unsigned short* wfF1 = (unsigned short*)(ws + 65536);       // 64 KB
    unsigned short* wfF2 = (unsigned short*)(ws + 131072);      // 128 KB
    float*          beta = (float*)(ws + 262144);               // 3 KB

    prep_kernel<<<256, 256, 0, stream>>>(pw0, pw1, w2,
                                         s0, b0, m0, v0,
                                         s1, b1, m1, v1,
                                         s2, b2, m2, v2,
                                         wfF0, wfF1, wfF2, beta);

    fused_kernel<<<2048, 512, 0, stream>>>(x, wts, idx, dw0, dw1,
                                           wfF0, wfF1, wfF2, beta, (float*)d_out);
}

// Round 7
// 92.362 us; speedup vs baseline: 2.5348x; 1.9229x over previous
//
#include <hip/hip_runtime.h>

typedef __bf16 bf16x8 __attribute__((ext_vector_type(8)));
typedef float f32x4 __attribute__((ext_vector_type(4)));

#define BN_EPS 1e-5f

__device__ __forceinline__ unsigned short f2bf(float f) {
    union { float f; unsigned u; } x; x.f = f;
    unsigned r = x.u + 0x7fffu + ((x.u >> 16) & 1u);
    return (unsigned short)(r >> 16);
}

__device__ __forceinline__ unsigned pk_bf16(float lo, float hi) {
    unsigned r;
    asm("v_cvt_pk_bf16_f32 %0, %1, %2" : "=v"(r) : "v"(lo), "v"(hi));
    return r;
}

// ---------------- prepass: fold BN scale into weights, FRAGMENT-CONTIGUOUS layout ----
// wfF[e]: frag for koct q=k/8, outch o at ((q*256 + o)*8 + (k&7)).
__global__ void prep_kernel(const float* __restrict__ pw0, const float* __restrict__ pw1,
                            const float* __restrict__ w2,
                            const float* __restrict__ s0, const float* __restrict__ b0,
                            const float* __restrict__ m0, const float* __restrict__ v0,
                            const float* __restrict__ s1, const float* __restrict__ b1,
                            const float* __restrict__ m1, const float* __restrict__ v1,
                            const float* __restrict__ s2, const float* __restrict__ b2,
                            const float* __restrict__ m2, const float* __restrict__ v2,
                            unsigned short* __restrict__ wfF0, unsigned short* __restrict__ wfF1,
                            unsigned short* __restrict__ wfF2, float* __restrict__ beta) {
    int o = blockIdx.x;     // 0..255 outch
    int t = threadIdx.x;    // 0..255 k
    float inv0 = s0[o] * rsqrtf(v0[o] + BN_EPS);
    float inv1 = s1[o] * rsqrtf(v1[o] + BN_EPS);
    float inv2 = s2[o] * rsqrtf(v2[o] + BN_EPS);
    if (t == 0) {
        beta[0 * 256 + o] = b0[o] - m0[o] * inv0;
        beta[1 * 256 + o] = b1[o] - m1[o] * inv1;
        beta[2 * 256 + o] = b2[o] - m2[o] * inv2;
    }
    if (t < 128) {
        wfF0[((t >> 3) * 256 + o) * 8 + (t & 7)] = f2bf(pw0[o * 128 + t] * inv0);
        wfF1[((t >> 3) * 256 + o) * 8 + (t & 7)] = f2bf(pw1[o * 128 + t] * inv1);
    }
    wfF2[((t >> 3) * 256 + o) * 8 + (t & 7)] = f2bf(w2[o * 256 + t] * inv2);
}

// ---------------- GEMM helper: r2 structure (kk-outer, depth-1 prefetch) --------------
// B-tile: [64 px][256 K] bf16, px-major 512 B/px, 16-B col c stored at c ^ ((px&15)<<4).
template<int NK>
__device__ __forceinline__ void gemm_expert(const char* lds, const unsigned short* __restrict__ W,
                                            int qb, int wave, int l15, int l4,
                                            const int* pxv, const int* swv, f32x4 acc[2][4]) {
    const int row0 = wave * 32 + l15;
    bf16x8 aC[2], bC[4];
#pragma unroll
    for (int ot = 0; ot < 2; ++ot)
        aC[ot] = *(const bf16x8*)(W + (l4 * 256 + row0 + ot * 16) * 8);
#pragma unroll
    for (int tp = 0; tp < 4; ++tp)
        bC[tp] = *(const bf16x8*)(lds + pxv[tp] * 512 + ((qb + l4 * 16) ^ swv[tp]));

#pragma unroll
    for (int kk = 0; kk < NK; ++kk) {
        bf16x8 aN[2], bN[4];
        if (kk + 1 < NK) {
#pragma unroll
            for (int ot = 0; ot < 2; ++ot)
                aN[ot] = *(const bf16x8*)(W + (((kk + 1) * 4 + l4) * 256 + row0 + ot * 16) * 8);
#pragma unroll
            for (int tp = 0; tp < 4; ++tp)
                bN[tp] = *(const bf16x8*)(lds + pxv[tp] * 512 + ((qb + (kk + 1) * 64 + l4 * 16) ^ swv[tp]));
        }
#pragma unroll
        for (int ot = 0; ot < 2; ++ot)
#pragma unroll
            for (int tp = 0; tp < 4; ++tp)
                acc[ot][tp] = __builtin_amdgcn_mfma_f32_16x16x32_bf16(aC[ot], bC[tp], acc[ot][tp], 0, 0, 0);
        if (kk + 1 < NK) {
#pragma unroll
            for (int ot = 0; ot < 2; ++ot) aC[ot] = aN[ot];
#pragma unroll
            for (int tp = 0; tp < 4; ++tp) bC[tp] = bN[tp];
        }
    }
}

__device__ __forceinline__ void epilogue(const f32x4 acc[2][4], float ce, const float* __restrict__ bp,
                                         int wave, int l4, f32x4 res[2][4]) {
#pragma unroll
    for (int ot = 0; ot < 2; ++ot)
#pragma unroll
        for (int j = 0; j < 4; ++j) {
            const int o = wave * 32 + ot * 16 + l4 * 4 + j;
            const float bet = bp[o];
#pragma unroll
            for (int tp = 0; tp < 4; ++tp) {
                float v = acc[ot][tp][j] + bet;
                float sig = __builtin_amdgcn_rcpf(1.f + __expf(-v));
                res[ot][tp][j] += ce * (v * sig);
            }
        }
}

// ---------------- main fused kernel: 1 WG per (b,h) row, 8 waves, 2 K-passes ----------
__global__ __launch_bounds__(512, 4)
void fused_kernel(const float* __restrict__ x,
                  const float* __restrict__ wts, const int* __restrict__ idx,
                  const float* __restrict__ dw0, const float* __restrict__ dw1,
                  const unsigned short* __restrict__ wfF0,
                  const unsigned short* __restrict__ wfF1,
                  const unsigned short* __restrict__ wfF2,
                  const float* __restrict__ beta,
                  float* __restrict__ out) {
    __shared__ __align__(16) char lds[34816];        // B-tile 32 KB; transpose 34.8 KB

    const int tid  = threadIdx.x;
    const int wave = tid >> 6;
    const int lane = tid & 63;

    const int bid = blockIdx.x;
    const int nb  = ((bid & 7) << 8) | (bid >> 3);   // XCD swizzle, bijective on 2048
    const int b   = nb >> 6;
    const int h   = nb & 63;

    float c0 = 0.f, c1 = 0.f, c2 = 0.f;
#pragma unroll
    for (int t = 0; t < 2; ++t) {
        int e = idx[b * 2 + t];
        float w = wts[b * 2 + t];
        if (e == 0) c0 += w;
        else if (e == 1) c1 += w;
        else if (e == 2) c2 += w;
    }
    const bool do0 = (c0 != 0.f), do1 = (c1 != 0.f), do2 = (c2 != 0.f);

    const long rowBase = (long)b * 1048576L;

    const int g   = lane >> 2;                       // px-group 0..15
    const int kq  = lane & 3;
    const int px0 = g * 4;
    const int l15 = lane & 15;
    const int l4  = lane >> 4;
    const float* xb = x + rowBase + h * 64 + px0;
    const bool hm = (h > 0), hp = (h < 63);

    f32x4 res[2][4];
#pragma unroll
    for (int ot = 0; ot < 2; ++ot)
#pragma unroll
        for (int tp = 0; tp < 4; ++tp)
            res[ot][tp] = (f32x4){0.f, 0.f, 0.f, 0.f};

    int pxv[4], swv[4];
#pragma unroll
    for (int tp = 0; tp < 4; ++tp) {
        pxv[tp] = tp * 16 + l15;
        swv[tp] = (pxv[tp] & 15) << 4;
    }

    // ================= pass 1: depthwise experts (K 0..255 = dw0 | dw1) ==============
    if (do0 || do1) {
        // waves 0-3 stage ch 0..127 (expert0), waves 4-7 stage ch 128..255 (expert1)
        if ((wave < 4) ? do0 : do1) {
#pragma unroll
            for (int i = 0; i < 2; ++i) {
                const int k0 = wave * 32 + i * 16 + kq * 4;
                unsigned dw_p[2][4];
#pragma unroll
                for (int pr = 0; pr < 2; ++pr) {
                    float y[2][4];
#pragma unroll
                    for (int k2 = 0; k2 < 2; ++k2) {
                        const int k = k0 + pr * 2 + k2;
                        const float* dwp = (k < 128) ? (dw0 + k * 9) : (dw1 + (k - 128) * 9);
                        const float* xc = xb + (long)k * 4096;
                        float4 rm = hm ? *(const float4*)(xc - 64) : make_float4(0.f, 0.f, 0.f, 0.f);
                        float4 rc = *(const float4*)(xc);
                        float4 rp = hp ? *(const float4*)(xc + 64) : make_float4(0.f, 0.f, 0.f, 0.f);
                        float lm = __shfl_up(rm.w, 4), lc = __shfl_up(rc.w, 4), lp = __shfl_up(rp.w, 4);
                        float Rm = __shfl_down(rm.x, 4), Rc = __shfl_down(rc.x, 4), Rp = __shfl_down(rp.x, 4);
                        if (g == 0)  { lm = 0.f; lc = 0.f; lp = 0.f; }
                        if (g == 15) { Rm = 0.f; Rc = 0.f; Rp = 0.f; }
                        const float w0 = dwp[0], w1 = dwp[1], w2 = dwp[2];
                        const float w3 = dwp[3], w4 = dwp[4], w5 = dwp[5];
                        const float w6 = dwp[6], w7 = dwp[7], w8 = dwp[8];
                        y[k2][0] = w0*lm   + w1*rm.x + w2*rm.y + w3*lc   + w4*rc.x + w5*rc.y + w6*lp   + w7*rp.x + w8*rp.y;
                        y[k2][1] = w0*rm.x + w1*rm.y + w2*rm.z + w3*rc.x + w4*rc.y + w5*rc.z + w6*rp.x + w7*rp.y + w8*rp.z;
                        y[k2][2] = w0*rm.y + w1*rm.z + w2*rm.w + w3*rc.y + w4*rc.z + w5*rc.w + w6*rp.y + w7*rp.z + w8*rp.w;
                        y[k2][3] = w0*rm.z + w1*rm.w + w2*Rm   + w3*rc.z + w4*rc.w + w5*Rc   + w6*rp.z + w7*rp.w + w8*Rp;
                    }
#pragma unroll
                    for (int j = 0; j < 4; ++j)
                        dw_p[pr][j] = pk_bf16(y[0][j], y[1][j]);
                }
                const int colb = (k0 >> 3) * 16;
                const int sub  = (k0 & 4) * 2;
#pragma unroll
                for (int j = 0; j < 4; ++j) {
                    const int px = px0 + j;
                    *(uint2*)(lds + px * 512 + ((colb ^ ((px & 15) << 4))) + sub) =
                        make_uint2(dw_p[0][j], dw_p[1][j]);
                }
            }
        }
        __syncthreads();
        if (do0) {
            f32x4 acc[2][4];
#pragma unroll
            for (int ot = 0; ot < 2; ++ot)
#pragma unroll
                for (int tp = 0; tp < 4; ++tp) acc[ot][tp] = (f32x4){0.f, 0.f, 0.f, 0.f};
            gemm_expert<4>(lds, wfF0, 0, wave, l15, l4, pxv, swv, acc);
            epilogue(acc, c0, beta, wave, l4, res);
        }
        if (do1) {
            f32x4 acc[2][4];
#pragma unroll
            for (int ot = 0; ot < 2; ++ot)
#pragma unroll
                for (int tp = 0; tp < 4; ++tp) acc[ot][tp] = (f32x4){0.f, 0.f, 0.f, 0.f};
            gemm_expert<4>(lds, wfF1, 256, wave, l15, l4, pxv, swv, acc);
            epilogue(acc, c1, beta + 256, wave, l4, res);
        }
    }

    // ================= pass 2: raw expert (K 0..255 = x channels) ====================
    if (do2) {
        __syncthreads();                             // pass-1 readers done before overwrite
        {
            const int cb = wave * 32 + kq * 8;       // 8 channels
            float4 r[8];
#pragma unroll
            for (int c = 0; c < 8; ++c)
                r[c] = *(const float4*)(xb + (long)(cb + c) * 4096);
            const int colb = (cb >> 3) * 16;
#pragma unroll
            for (int j = 0; j < 4; ++j) {
                const int px = px0 + j;
                float v0 = (j == 0) ? r[0].x : (j == 1) ? r[0].y : (j == 2) ? r[0].z : r[0].w;
                float v1 = (j == 0) ? r[1].x : (j == 1) ? r[1].y : (j == 2) ? r[1].z : r[1].w;
                float v2 = (j == 0) ? r[2].x : (j == 1) ? r[2].y : (j == 2) ? r[2].z : r[2].w;
                float v3 = (j == 0) ? r[3].x : (j == 1) ? r[3].y : (j == 2) ? r[3].z : r[3].w;
                float v4 = (j == 0) ? r[4].x : (j == 1) ? r[4].y : (j == 2) ? r[4].z : r[4].w;
                float v5 = (j == 0) ? r[5].x : (j == 1) ? r[5].y : (j == 2) ? r[5].z : r[5].w;
                float v6 = (j == 0) ? r[6].x : (j == 1) ? r[6].y : (j == 2) ? r[6].z : r[6].w;
                float v7 = (j == 0) ? r[7].x : (j == 1) ? r[7].y : (j == 2) ? r[7].z : r[7].w;
                *(uint4*)(lds + px * 512 + ((colb ^ ((px & 15) << 4)))) =
                    make_uint4(pk_bf16(v0, v1), pk_bf16(v2, v3), pk_bf16(v4, v5), pk_bf16(v6, v7));
            }
        }
        __syncthreads();
        {
            f32x4 acc[2][4];
#pragma unroll
            for (int ot = 0; ot < 2; ++ot)
#pragma unroll
                for (int tp = 0; tp < 4; ++tp) acc[ot][tp] = (f32x4){0.f, 0.f, 0.f, 0.f};
            gemm_expert<8>(lds, wfF2, 0, wave, l15, l4, pxv, swv, acc);
            epilogue(acc, c2, beta + 512, wave, l4, res);
        }
    }

    // ================= store: transpose through LDS, full-line writes ================
    float* lf = (float*)lds;
    const long outB = rowBase + h * 64;
    __syncthreads();
#pragma unroll
    for (int r = 0; r < 2; ++r) {
        if ((wave >> 2) == r) {
#pragma unroll
            for (int ot = 0; ot < 2; ++ot)
#pragma unroll
                for (int j = 0; j < 4; ++j) {
                    const int o = wave * 32 + ot * 16 + l4 * 4 + j;
#pragma unroll
                    for (int tp = 0; tp < 4; ++tp)
                        lf[(o & 127) * 68 + tp * 16 + l15] = res[ot][tp][j];
                }
        }
        __syncthreads();
        {
            const int rowq = tid >> 3;               // 0..63
            const int col  = (tid & 7) * 8;          // float index
#pragma unroll
            for (int rr = 0; rr < 2; ++rr) {
                const int lr = rowq + rr * 64;       // 0..127
                float4 v0 = *(float4*)&lf[lr * 68 + col];
                float4 v1 = *(float4*)&lf[lr * 68 + col + 4];
                float* op = out + outB + (long)(r * 128 + lr) * 4096 + col;
                *(float4*)op = v0;
                *(float4*)(op + 4) = v1;
            }
        }
        __syncthreads();
    }
}

extern "C" void kernel_launch(void* const* d_in, const int* in_sizes, int n_in,
                              void* d_out, int out_size, void* d_ws, size_t ws_size,
                              hipStream_t stream) {
    const float* x    = (const float*)d_in[0];
    const float* wts  = (const float*)d_in[1];
    const int*   idx  = (const int*)d_in[2];
    const float* dw0  = (const float*)d_in[3];
    const float* pw0  = (const float*)d_in[4];
    const float* s0   = (const float*)d_in[5];
    const float* b0   = (const float*)d_in[6];
    const float* m0   = (const float*)d_in[7];
    const float* v0   = (const float*)d_in[8];
    const float* dw1  = (const float*)d_in[9];
    const float* pw1  = (const float*)d_in[10];
    const float* s1   = (const float*)d_in[11];
    const float* b1   = (const float*)d_in[12];
    const float* m1   = (const float*)d_in[13];
    const float* v1   = (const float*)d_in[14];
    const float* w2   = (const float*)d_in[15];
    const float* s2   = (const float*)d_in[16];
    const float* b2   = (const float*)d_in[17];
    const float* m2   = (const float*)d_in[18];
    const float* v2   = (const float*)d_in[19];

    char* ws = (char*)d_ws;
    unsigned short* wfF0 = (unsigned short*)ws;                 // 64 KB
    unsigned short* wfF1 = (unsigned short*)(ws + 65536);       // 64 KB
    unsigned short* wfF2 = (unsigned short*)(ws + 131072);      // 128 KB
    float*          beta = (float*)(ws + 262144);               // 3 KB

    prep_kernel<<<256, 256, 0, stream>>>(pw0, pw1, w2,
                                         s0, b0, m0, v0,
                                         s1, b1, m1, v1,
                                         s2, b2, m2, v2,
                                         wfF0, wfF1, wfF2, beta);

    fused_kernel<<<2048, 512, 0, stream>>>(x, wts, idx, dw0, dw1,
                                           wfF0, wfF1, wfF2, beta, (float*)d_out);
}